// Round 1
// baseline (758.117 us; speedup 1.0000x reference)
//
#include <hip/hip_runtime.h>
#include <math.h>

#define BB 2
#define LL 2048
#define DMM 512
#define HH 8
#define DD 64
#define NUMK 40
#define NUMQ 40
#define LNEPS 1e-5f

// ---------------- K1: projection  Out = X @ W + bias  (fp32) ----------------
// Block: 512 threads (one per output col), 16 rows per block.
// X reads are wave-uniform (row0 from blockIdx, d from loop) -> scalar loads.
// W reads coalesced across threads (W[d][j], consecutive j).
__global__ __launch_bounds__(512) void proj_kernel(const float* __restrict__ X,
                                                   const float* __restrict__ W,
                                                   const float* __restrict__ bias,
                                                   float* __restrict__ Out) {
    const int j = threadIdx.x;
    const int row0 = blockIdx.x * 16;
    float acc[16];
#pragma unroll
    for (int r = 0; r < 16; ++r) acc[r] = 0.f;
    const float* xbase = X + (size_t)row0 * DMM;
    for (int d = 0; d < DMM; ++d) {
        float w = W[(size_t)d * DMM + j];
#pragma unroll
        for (int r = 0; r < 16; ++r)
            acc[r] = fmaf(xbase[(size_t)r * DMM + d], w, acc[r]);
    }
    float bv = bias[j];
#pragma unroll
    for (int r = 0; r < 16; ++r)
        Out[(size_t)(row0 + r) * DMM + j] = acc[r] + bv;
}

// ---------------- K2: measure[b,h,i] = max_j pre - sum_j pre / L ------------
// One wave (64 lanes) per query; lane = d. qp/kp layout: (B,L,H,D) flat.
__global__ __launch_bounds__(256) void measure_kernel(const float* __restrict__ qp,
                                                      const float* __restrict__ kp,
                                                      const int* __restrict__ rnd,
                                                      float* __restrict__ measure) {
    const int lane = threadIdx.x & 63;
    const int wv = threadIdx.x >> 6;
    const int gq = blockIdx.x * 4 + wv;     // ((b*H+h)*L + i)
    const int i = gq & (LL - 1);
    const int bh = gq >> 11;
    const int h = bh & (HH - 1);
    const int b = bh >> 3;
    const float qv = qp[(((size_t)(b * LL + i)) * HH + h) * DD + lane];
    float mx = -INFINITY, tot = 0.f;
    for (int jj = 0; jj < NUMK; ++jj) {
        int idx = rnd[i * NUMK + jj];
        float kv = kp[(((size_t)(b * LL + idx)) * HH + h) * DD + lane];
        float p = qv * kv;
#pragma unroll
        for (int off = 32; off > 0; off >>= 1) p += __shfl_xor(p, off, 64);
        mx = fmaxf(mx, p);
        tot += p;
    }
    if (lane == 0) measure[gq] = mx - tot * (1.0f / LL);
}

// ---------------- K3: exact top-40 per (b,h), lax.top_k tie semantics -------
__global__ __launch_bounds__(256) void topk_kernel(const float* __restrict__ measure,
                                                   int* __restrict__ q_idx,
                                                   int* __restrict__ sel_pos) {
    __shared__ float ms[LL];
    __shared__ float rv[256];
    __shared__ int ri[256];
    const int t = threadIdx.x;
    const int bh = blockIdx.x;
    for (int i = t; i < LL; i += 256) {
        ms[i] = measure[(size_t)bh * LL + i];
        sel_pos[(size_t)bh * LL + i] = -1;
    }
    __syncthreads();
    for (int it = 0; it < NUMQ; ++it) {
        float bv = -INFINITY; int bi = 0x7fffffff;
        // ascending index scan with strict '>' keeps lowest index on ties
        for (int i = t; i < LL; i += 256) {
            float v = ms[i];
            if (v > bv) { bv = v; bi = i; }
        }
        rv[t] = bv; ri[t] = bi;
        __syncthreads();
        for (int s = 128; s > 0; s >>= 1) {
            if (t < s) {
                float ov = rv[t + s]; int oi = ri[t + s];
                if (ov > rv[t] || (ov == rv[t] && oi < ri[t])) { rv[t] = ov; ri[t] = oi; }
            }
            __syncthreads();
        }
        if (t == 0) {
            int qi = ri[0];
            q_idx[bh * NUMQ + it] = qi;
            sel_pos[(size_t)bh * LL + qi] = it;
            ms[qi] = -INFINITY;
        }
        __syncthreads();
    }
}

// ---------------- K4: per (b,h,p): scores -> softmax -> attn out + PV -------
__global__ __launch_bounds__(256) void attn_kernel(const float* __restrict__ qp,
                                                   const float* __restrict__ kp,
                                                   const float* __restrict__ vp,
                                                   const int* __restrict__ q_idx,
                                                   float* __restrict__ attn_out,
                                                   float* __restrict__ out_sel) {
    __shared__ float qs[DD];
    __shared__ float sc[LL];
    __shared__ float red[256];
    __shared__ float pv[4 * DD];
    const int t = threadIdx.x;
    const int blk = blockIdx.x;           // bh*NUMQ + p
    const int p = blk % NUMQ;
    const int bh = blk / NUMQ;
    const int h = bh & (HH - 1);
    const int b = bh >> 3;
    const int qi = q_idx[bh * NUMQ + p];
    if (t < DD) qs[t] = qp[(((size_t)(b * LL + qi)) * HH + h) * DD + t];
    __syncthreads();
    const float scale = 0.125f;            // D^-0.5
    for (int l = t; l < LL; l += 256) {
        const float* krow = kp + (((size_t)(b * LL + l)) * HH + h) * DD;
        float dot = 0.f;
#pragma unroll
        for (int d = 0; d < DD; ++d) dot = fmaf(qs[d], krow[d], dot);
        sc[l] = dot * scale;
    }
    __syncthreads();
    float mx = -INFINITY;
    for (int l = t; l < LL; l += 256) mx = fmaxf(mx, sc[l]);
    red[t] = mx;
    __syncthreads();
    for (int s = 128; s > 0; s >>= 1) { if (t < s) red[t] = fmaxf(red[t], red[t + s]); __syncthreads(); }
    mx = red[0];
    __syncthreads();
    float psum = 0.f;
    for (int l = t; l < LL; l += 256) { float e = expf(sc[l] - mx); sc[l] = e; psum += e; }
    red[t] = psum;
    __syncthreads();
    for (int s = 128; s > 0; s >>= 1) { if (t < s) red[t] += red[t + s]; __syncthreads(); }
    const float inv = 1.0f / red[0];
    float* arow = attn_out + (size_t)blk * LL;
    for (int l = t; l < LL; l += 256) arow[l] = sc[l] * inv;
    // PV: group g (wave) strides l, lane d coalesced over vp row
    const int d = t & 63, g = t >> 6;
    float acc = 0.f;
    for (int l = g; l < LL; l += 4)
        acc = fmaf(sc[l], vp[(((size_t)(b * LL + l)) * HH + h) * DD + d], acc);
    acc *= inv;
    pv[g * DD + d] = acc;
    __syncthreads();
    if (t < DD)
        out_sel[((size_t)bh * NUMQ + p) * DD + t] =
            pv[t] + pv[DD + t] + pv[2 * DD + t] + pv[3 * DD + t];
}

// ---------------- K5: v_mean[b,h,d] = mean over L -----------------------
__global__ __launch_bounds__(256) void vmean_kernel(const float* __restrict__ vp,
                                                    float* __restrict__ v_mean) {
    __shared__ float pv[4 * DD];
    const int t = threadIdx.x;
    const int bh = blockIdx.x;
    const int h = bh & (HH - 1);
    const int b = bh >> 3;
    const int d = t & 63, g = t >> 6;
    float acc = 0.f;
    for (int l = g; l < LL; l += 4)
        acc += vp[(((size_t)(b * LL + l)) * HH + h) * DD + d];
    pv[g * DD + d] = acc;
    __syncthreads();
    if (t < DD)
        v_mean[bh * DD + t] = (pv[t] + pv[DD + t] + pv[2 * DD + t] + pv[3 * DD + t]) * (1.0f / LL);
}

// ---------------- K6: scatter + residual + LayerNorm ------------------------
__global__ __launch_bounds__(512) void final_kernel(const float* __restrict__ q_in,
                                                    const int* __restrict__ sel_pos,
                                                    const float* __restrict__ out_sel,
                                                    const float* __restrict__ v_mean,
                                                    const float* __restrict__ gamma,
                                                    const float* __restrict__ beta,
                                                    float* __restrict__ yout) {
    __shared__ float red[512];
    const int j = threadIdx.x;
    const int tok = blockIdx.x;          // b*L + l
    const int b = tok >> 11;
    const int l = tok & (LL - 1);
    const int h = j >> 6, d = j & 63;
    const int bh = b * HH + h;
    const int p = sel_pos[(size_t)bh * LL + l];
    float val = (p >= 0) ? out_sel[((size_t)bh * NUMQ + p) * DD + d]
                         : v_mean[bh * DD + d];
    float y = val + q_in[(size_t)tok * DMM + j];
    red[j] = y;
    __syncthreads();
    for (int s = 256; s > 0; s >>= 1) { if (j < s) red[j] += red[j + s]; __syncthreads(); }
    float mu = red[0] * (1.0f / DMM);
    __syncthreads();
    float dv = y - mu;
    red[j] = dv * dv;
    __syncthreads();
    for (int s = 256; s > 0; s >>= 1) { if (j < s) red[j] += red[j + s]; __syncthreads(); }
    float var = red[0] * (1.0f / DMM);
    float yn = dv * rsqrtf(var + LNEPS) * gamma[j] + beta[j];
    yout[(size_t)tok * DMM + j] = yn;
}

extern "C" void kernel_launch(void* const* d_in, const int* in_sizes, int n_in,
                              void* d_out, int out_size, void* d_ws, size_t ws_size,
                              hipStream_t stream) {
    const float* q     = (const float*)d_in[0];
    const float* k     = (const float*)d_in[1];
    const float* v     = (const float*)d_in[2];
    const float* Wq    = (const float*)d_in[3];
    const float* bq    = (const float*)d_in[4];
    const float* Wk    = (const float*)d_in[5];
    const float* bk    = (const float*)d_in[6];
    const float* Wv    = (const float*)d_in[7];
    const float* bv    = (const float*)d_in[8];
    const float* gamma = (const float*)d_in[9];
    const float* beta  = (const float*)d_in[10];
    const int*   rnd   = (const int*)d_in[11];

    float* ws = (float*)d_ws;
    float* qp      = ws;                                   // B*L*DM
    float* kp      = qp + (size_t)BB * LL * DMM;
    float* vp      = kp + (size_t)BB * LL * DMM;
    float* measure = vp + (size_t)BB * LL * DMM;           // B*H*L
    float* out_sel = measure + (size_t)BB * HH * LL;       // B*H*NUMQ*D
    float* v_mean  = out_sel + (size_t)BB * HH * NUMQ * DD;// B*H*D
    int*   q_idx   = (int*)(v_mean + (size_t)BB * HH * DD);// B*H*NUMQ
    int*   sel_pos = q_idx + BB * HH * NUMQ;               // B*H*L

    float* yn_out   = (float*)d_out;
    float* attn_out = yn_out + (size_t)BB * LL * DMM;

    proj_kernel<<<dim3(BB * LL / 16), 512, 0, stream>>>(q, Wq, bq, qp);
    proj_kernel<<<dim3(BB * LL / 16), 512, 0, stream>>>(k, Wk, bk, kp);
    proj_kernel<<<dim3(BB * LL / 16), 512, 0, stream>>>(v, Wv, bv, vp);
    measure_kernel<<<BB * HH * LL / 4, 256, 0, stream>>>(qp, kp, rnd, measure);
    topk_kernel<<<BB * HH, 256, 0, stream>>>(measure, q_idx, sel_pos);
    attn_kernel<<<BB * HH * NUMQ, 256, 0, stream>>>(qp, kp, vp, q_idx, attn_out, out_sel);
    vmean_kernel<<<BB * HH, 256, 0, stream>>>(vp, v_mean);
    final_kernel<<<BB * LL, 512, 0, stream>>>(q, sel_pos, out_sel, v_mean, gamma, beta, yn_out);
}

// Round 2
// 635.353 us; speedup vs baseline: 1.1932x; 1.1932x over previous
//
#include <hip/hip_runtime.h>
#include <math.h>

#define BB 2
#define LL 2048
#define DMM 512
#define HH 8
#define DD 64
#define NUMK 40
#define NUMQ 40
#define LNEPS 1e-5f

// ---------------- K1: projection  Out = X @ W + bias  (fp32) ----------------
// Writes head-major layout (B,H,L,D): Out[((b*H+h)*L + l)*D + d]
__global__ __launch_bounds__(512) void proj_kernel(const float* __restrict__ X,
                                                   const float* __restrict__ W,
                                                   const float* __restrict__ bias,
                                                   float* __restrict__ Out) {
    const int j = threadIdx.x;
    const int row0 = blockIdx.x * 16;
    float acc[16];
#pragma unroll
    for (int r = 0; r < 16; ++r) acc[r] = 0.f;
    const float* xbase = X + (size_t)row0 * DMM;
    for (int d = 0; d < DMM; ++d) {
        float w = W[(size_t)d * DMM + j];
#pragma unroll
        for (int r = 0; r < 16; ++r)
            acc[r] = fmaf(xbase[(size_t)r * DMM + d], w, acc[r]);
    }
    float bv = bias[j];
    const int h = j >> 6, dd = j & 63;
    const int b = row0 >> 11;
    const int l0 = row0 & (LL - 1);
#pragma unroll
    for (int r = 0; r < 16; ++r)
        Out[(((size_t)(b * HH + h)) * LL + l0 + r) * DD + dd] = acc[r] + bv;
}

// ---------------- K1b: transpose (B,H,L,D) -> (B,H,D,L) ---------------------
__global__ __launch_bounds__(256) void transpose_kernel(const float* __restrict__ src,
                                                        float* __restrict__ dst) {
    __shared__ float tile[64][65];
    const int bh = blockIdx.y;
    const int l0 = blockIdx.x * 64;
    const int d = threadIdx.x & 63;
    const int r0 = threadIdx.x >> 6;
    for (int rr = r0; rr < 64; rr += 4)
        tile[rr][d] = src[((size_t)bh * LL + l0 + rr) * DD + d];
    __syncthreads();
    const int li = threadIdx.x & 63;
    for (int dd = r0; dd < 64; dd += 4)
        dst[((size_t)bh * DD + dd) * LL + l0 + li] = tile[li][dd];
}

// ---------------- K2: measure[b,h,i] = max_j pre - sum_j pre / L ------------
// One wave per query; lane = d. qp2/kp2 layout (B,H,L,D).
__global__ __launch_bounds__(256) void measure_kernel(const float* __restrict__ qp2,
                                                      const float* __restrict__ kp2,
                                                      const int* __restrict__ rnd,
                                                      float* __restrict__ measure) {
    const int lane = threadIdx.x & 63;
    const int wv = threadIdx.x >> 6;
    const int gq = blockIdx.x * 4 + wv;     // bh*L + i
    const int i = gq & (LL - 1);
    const int bh = gq >> 11;
    const float qv = qp2[((size_t)bh * LL + i) * DD + lane];
    float mx = -INFINITY, tot = 0.f;
    for (int jj = 0; jj < NUMK; ++jj) {
        int idx = rnd[i * NUMK + jj];
        float kv = kp2[((size_t)bh * LL + idx) * DD + lane];
        float p = qv * kv;
#pragma unroll
        for (int off = 32; off > 0; off >>= 1) p += __shfl_xor(p, off, 64);
        mx = fmaxf(mx, p);
        tot += p;
    }
    if (lane == 0) measure[gq] = mx - tot * (1.0f / LL);
}

// ---------------- K3: exact top-40 per (b,h), lax.top_k tie semantics -------
__global__ __launch_bounds__(256) void topk_kernel(const float* __restrict__ measure,
                                                   int* __restrict__ q_idx,
                                                   int* __restrict__ sel_pos) {
    __shared__ float ms[LL];
    __shared__ float wvv[4];
    __shared__ int wvi[4];
    const int t = threadIdx.x;
    const int bh = blockIdx.x;
    for (int i = t; i < LL; i += 256) {
        ms[i] = measure[(size_t)bh * LL + i];
        sel_pos[(size_t)bh * LL + i] = -1;
    }
    __syncthreads();
    for (int it = 0; it < NUMQ; ++it) {
        float bv = -INFINITY; int bi = 0x7fffffff;
        for (int i = t; i < LL; i += 256) {
            float v = ms[i];
            if (v > bv) { bv = v; bi = i; }
        }
#pragma unroll
        for (int off = 32; off > 0; off >>= 1) {
            float ov = __shfl_xor(bv, off, 64);
            int   oi = __shfl_xor(bi, off, 64);
            if (ov > bv || (ov == bv && oi < bi)) { bv = ov; bi = oi; }
        }
        if ((t & 63) == 0) { wvv[t >> 6] = bv; wvi[t >> 6] = bi; }
        __syncthreads();
        if (t == 0) {
            float fv = wvv[0]; int fi = wvi[0];
#pragma unroll
            for (int u = 1; u < 4; ++u)
                if (wvv[u] > fv || (wvv[u] == fv && wvi[u] < fi)) { fv = wvv[u]; fi = wvi[u]; }
            q_idx[bh * NUMQ + it] = fi;
            sel_pos[(size_t)bh * LL + fi] = it;
            ms[fi] = -INFINITY;
        }
        __syncthreads();
    }
}

// ---------------- K4: per (b,h,p): scores -> softmax -> attn out + PV -------
// kpt layout (B,H,D,L); vp2 layout (B,H,L,D).
__global__ __launch_bounds__(256) void attn_kernel(const float* __restrict__ qp2,
                                                   const float* __restrict__ kpt,
                                                   const float* __restrict__ vp2,
                                                   const int* __restrict__ q_idx,
                                                   float* __restrict__ attn_out,
                                                   float* __restrict__ out_sel) {
    __shared__ float qs[DD];
    __shared__ float sc[LL];
    __shared__ float reda[4];
    __shared__ float redb[4];
    __shared__ float pvred[16][64];
    const int t = threadIdx.x;
    const int blk = blockIdx.x;           // bh*NUMQ + p
    const int p = blk % NUMQ;
    const int bh = blk / NUMQ;
    const int qi = q_idx[bh * NUMQ + p];
    if (t < DD) qs[t] = qp2[((size_t)bh * LL + qi) * DD + t];
    __syncthreads();

    // ---- scores: thread t owns keys [4t,4t+4) and [1024+4t,1024+4t+4) ----
    const float* kbase = kpt + (size_t)bh * DD * LL;
    float4 a0 = make_float4(0.f, 0.f, 0.f, 0.f);
    float4 a1 = make_float4(0.f, 0.f, 0.f, 0.f);
    for (int d = 0; d < DD; ++d) {
        const float qv = qs[d];
        const float4 k0 = *(const float4*)(kbase + (size_t)d * LL + 4 * t);
        const float4 k1 = *(const float4*)(kbase + (size_t)d * LL + 1024 + 4 * t);
        a0.x = fmaf(qv, k0.x, a0.x); a0.y = fmaf(qv, k0.y, a0.y);
        a0.z = fmaf(qv, k0.z, a0.z); a0.w = fmaf(qv, k0.w, a0.w);
        a1.x = fmaf(qv, k1.x, a1.x); a1.y = fmaf(qv, k1.y, a1.y);
        a1.z = fmaf(qv, k1.z, a1.z); a1.w = fmaf(qv, k1.w, a1.w);
    }
    const float scale = 0.125f;
    a0.x *= scale; a0.y *= scale; a0.z *= scale; a0.w *= scale;
    a1.x *= scale; a1.y *= scale; a1.z *= scale; a1.w *= scale;

    // ---- block max ----
    float mx = fmaxf(fmaxf(fmaxf(a0.x, a0.y), fmaxf(a0.z, a0.w)),
                     fmaxf(fmaxf(a1.x, a1.y), fmaxf(a1.z, a1.w)));
#pragma unroll
    for (int off = 32; off > 0; off >>= 1) mx = fmaxf(mx, __shfl_xor(mx, off, 64));
    if ((t & 63) == 0) reda[t >> 6] = mx;
    __syncthreads();
    mx = fmaxf(fmaxf(reda[0], reda[1]), fmaxf(reda[2], reda[3]));

    // ---- exp + store to LDS + partial sum ----
    a0.x = __expf(a0.x - mx); a0.y = __expf(a0.y - mx);
    a0.z = __expf(a0.z - mx); a0.w = __expf(a0.w - mx);
    a1.x = __expf(a1.x - mx); a1.y = __expf(a1.y - mx);
    a1.z = __expf(a1.z - mx); a1.w = __expf(a1.w - mx);
    *(float4*)&sc[4 * t] = a0;
    *(float4*)&sc[1024 + 4 * t] = a1;
    float psum = (a0.x + a0.y + a0.z + a0.w) + (a1.x + a1.y + a1.z + a1.w);
#pragma unroll
    for (int off = 32; off > 0; off >>= 1) psum += __shfl_xor(psum, off, 64);
    if ((t & 63) == 0) redb[t >> 6] = psum;
    __syncthreads();
    const float inv = 1.0f / (redb[0] + redb[1] + redb[2] + redb[3]);

    // ---- attn output (normalized) ----
    float* arow = attn_out + (size_t)blk * LL;
    float4 w0 = make_float4(a0.x * inv, a0.y * inv, a0.z * inv, a0.w * inv);
    float4 w1 = make_float4(a1.x * inv, a1.y * inv, a1.z * inv, a1.w * inv);
    *(float4*)&arow[4 * t] = w0;
    *(float4*)&arow[1024 + 4 * t] = w1;

    // ---- PV: lane group covers d via float4; sc broadcast from LDS ----
    const int dq = (t & 15) * 4;      // d quad
    const int lg = t >> 4;            // 0..15
    const float* vbase = vp2 + (size_t)bh * LL * DD + dq;
    float4 acc = make_float4(0.f, 0.f, 0.f, 0.f);
    for (int l = lg; l < LL; l += 16) {
        const float pr = sc[l];
        const float4 vv = *(const float4*)(vbase + (size_t)l * DD);
        acc.x = fmaf(pr, vv.x, acc.x); acc.y = fmaf(pr, vv.y, acc.y);
        acc.z = fmaf(pr, vv.z, acc.z); acc.w = fmaf(pr, vv.w, acc.w);
    }
    *(float4*)&pvred[lg][dq] = acc;
    __syncthreads();
    if (t < DD) {
        float s = 0.f;
#pragma unroll
        for (int u = 0; u < 16; ++u) s += pvred[u][t];
        out_sel[((size_t)bh * NUMQ + p) * DD + t] = s * inv;
    }
}

// ---------------- K5: v_mean[b,h,d] = mean over L ---------------------------
__global__ __launch_bounds__(256) void vmean_kernel(const float* __restrict__ vp2,
                                                    float* __restrict__ v_mean) {
    __shared__ float pv[4 * DD];
    const int t = threadIdx.x;
    const int bh = blockIdx.x;
    const int d = t & 63, g = t >> 6;
    float acc = 0.f;
    for (int l = g; l < LL; l += 4)
        acc += vp2[((size_t)bh * LL + l) * DD + d];
    pv[g * DD + d] = acc;
    __syncthreads();
    if (t < DD)
        v_mean[bh * DD + t] = (pv[t] + pv[DD + t] + pv[2 * DD + t] + pv[3 * DD + t]) * (1.0f / LL);
}

// ---------------- K6: scatter + residual + LayerNorm ------------------------
__global__ __launch_bounds__(512) void final_kernel(const float* __restrict__ q_in,
                                                    const int* __restrict__ sel_pos,
                                                    const float* __restrict__ out_sel,
                                                    const float* __restrict__ v_mean,
                                                    const float* __restrict__ gamma,
                                                    const float* __restrict__ beta,
                                                    float* __restrict__ yout) {
    __shared__ float red[512];
    const int j = threadIdx.x;
    const int tok = blockIdx.x;          // b*L + l
    const int b = tok >> 11;
    const int l = tok & (LL - 1);
    const int h = j >> 6, d = j & 63;
    const int bh = b * HH + h;
    const int p = sel_pos[(size_t)bh * LL + l];
    float val = (p >= 0) ? out_sel[((size_t)bh * NUMQ + p) * DD + d]
                         : v_mean[bh * DD + d];
    float y = val + q_in[(size_t)tok * DMM + j];
    red[j] = y;
    __syncthreads();
    for (int s = 256; s > 0; s >>= 1) { if (j < s) red[j] += red[j + s]; __syncthreads(); }
    float mu = red[0] * (1.0f / DMM);
    __syncthreads();
    float dv = y - mu;
    red[j] = dv * dv;
    __syncthreads();
    for (int s = 256; s > 0; s >>= 1) { if (j < s) red[j] += red[j + s]; __syncthreads(); }
    float var = red[0] * (1.0f / DMM);
    float yn = dv * rsqrtf(var + LNEPS) * gamma[j] + beta[j];
    yout[(size_t)tok * DMM + j] = yn;
}

extern "C" void kernel_launch(void* const* d_in, const int* in_sizes, int n_in,
                              void* d_out, int out_size, void* d_ws, size_t ws_size,
                              hipStream_t stream) {
    const float* q     = (const float*)d_in[0];
    const float* k     = (const float*)d_in[1];
    const float* v     = (const float*)d_in[2];
    const float* Wq    = (const float*)d_in[3];
    const float* bq    = (const float*)d_in[4];
    const float* Wk    = (const float*)d_in[5];
    const float* bk    = (const float*)d_in[6];
    const float* Wv    = (const float*)d_in[7];
    const float* bv    = (const float*)d_in[8];
    const float* gamma = (const float*)d_in[9];
    const float* beta  = (const float*)d_in[10];
    const int*   rnd   = (const int*)d_in[11];

    float* ws = (float*)d_ws;
    const size_t proj_sz = (size_t)BB * HH * LL * DD;      // = B*L*DM
    float* qp2     = ws;
    float* kp2     = qp2 + proj_sz;
    float* vp2     = kp2 + proj_sz;
    float* kpt     = vp2 + proj_sz;
    float* measure = kpt + proj_sz;                        // B*H*L
    float* out_sel = measure + (size_t)BB * HH * LL;       // B*H*NUMQ*D
    float* v_mean  = out_sel + (size_t)BB * HH * NUMQ * DD;// B*H*D
    int*   q_idx   = (int*)(v_mean + (size_t)BB * HH * DD);// B*H*NUMQ
    int*   sel_pos = q_idx + BB * HH * NUMQ;               // B*H*L

    float* yn_out   = (float*)d_out;
    float* attn_out = yn_out + (size_t)BB * LL * DMM;

    proj_kernel<<<dim3(BB * LL / 16), 512, 0, stream>>>(q, Wq, bq, qp2);
    proj_kernel<<<dim3(BB * LL / 16), 512, 0, stream>>>(k, Wk, bk, kp2);
    proj_kernel<<<dim3(BB * LL / 16), 512, 0, stream>>>(v, Wv, bv, vp2);
    transpose_kernel<<<dim3(LL / 64, BB * HH), 256, 0, stream>>>(kp2, kpt);
    measure_kernel<<<BB * HH * LL / 4, 256, 0, stream>>>(qp2, kp2, rnd, measure);
    topk_kernel<<<BB * HH, 256, 0, stream>>>(measure, q_idx, sel_pos);
    attn_kernel<<<BB * HH * NUMQ, 256, 0, stream>>>(qp2, kpt, vp2, q_idx, attn_out, out_sel);
    vmean_kernel<<<BB * HH, 256, 0, stream>>>(vp2, v_mean);
    final_kernel<<<BB * LL, 512, 0, stream>>>(q, sel_pos, out_sel, v_mean, gamma, beta, yn_out);
}

// Round 3
// 380.133 us; speedup vs baseline: 1.9943x; 1.6714x over previous
//
#include <hip/hip_runtime.h>
#include <math.h>

#define BB 2
#define LL 2048
#define DMM 512
#define HH 8
#define DD 64
#define NUMK 40
#define NUMQ 40
#define LNEPS 1e-5f

// ---------------- K1: fused projections, LDS-tiled fp32 GEMM ----------------
// grid (M/64, N/64, 3); block 256; 64x64 tile, 4x4 micro-tile, KC=32.
// Writes head-major (B,H,L,D).
__global__ __launch_bounds__(256) void proj_gemm_kernel(
    const float* __restrict__ Xq, const float* __restrict__ Xk, const float* __restrict__ Xv,
    const float* __restrict__ Wq, const float* __restrict__ Wk, const float* __restrict__ Wv,
    const float* __restrict__ bq, const float* __restrict__ bk, const float* __restrict__ bv,
    float* __restrict__ Oq, float* __restrict__ Ok, float* __restrict__ Ov) {
    const float* X; const float* W; const float* bias; float* Out;
    if (blockIdx.z == 0)      { X = Xq; W = Wq; bias = bq; Out = Oq; }
    else if (blockIdx.z == 1) { X = Xk; W = Wk; bias = bk; Out = Ok; }
    else                      { X = Xv; W = Wv; bias = bv; Out = Ov; }

    __shared__ float Xs[32][64];   // [kk][m]  (k-major for vector compute reads)
    __shared__ float Ws[32][64];   // [kk][j]

    const int t = threadIdx.x;
    const int tx = t & 15;         // col group (4 cols)
    const int ty = t >> 4;         // row group (4 rows)
    const int m0 = blockIdx.x * 64;
    const int j0 = blockIdx.y * 64;

    // staging maps
    const int wr0 = t >> 4;               // W rows 0..15, second: +16
    const int wc4 = (t & 15) * 4;
    const int xm0 = t >> 3;               // X m 0..31, second: +32
    const int xkq = (t & 7) * 4;

    float4 wA0, wA1, xA0, xA1;
    // prefetch chunk 0
    {
        const int k0 = 0;
        wA0 = *(const float4*)(W + (size_t)(k0 + wr0) * DMM + j0 + wc4);
        wA1 = *(const float4*)(W + (size_t)(k0 + wr0 + 16) * DMM + j0 + wc4);
        xA0 = *(const float4*)(X + (size_t)(m0 + xm0) * DMM + k0 + xkq);
        xA1 = *(const float4*)(X + (size_t)(m0 + xm0 + 32) * DMM + k0 + xkq);
    }

    float acc[4][4];
#pragma unroll
    for (int r = 0; r < 4; ++r)
#pragma unroll
        for (int c = 0; c < 4; ++c) acc[r][c] = 0.f;

    for (int ch = 0; ch < 16; ++ch) {
        __syncthreads();
        *(float4*)&Ws[wr0][wc4] = wA0;
        *(float4*)&Ws[wr0 + 16][wc4] = wA1;
        Xs[xkq + 0][xm0] = xA0.x; Xs[xkq + 1][xm0] = xA0.y;
        Xs[xkq + 2][xm0] = xA0.z; Xs[xkq + 3][xm0] = xA0.w;
        Xs[xkq + 0][xm0 + 32] = xA1.x; Xs[xkq + 1][xm0 + 32] = xA1.y;
        Xs[xkq + 2][xm0 + 32] = xA1.z; Xs[xkq + 3][xm0 + 32] = xA1.w;
        __syncthreads();
        if (ch < 15) {
            const int k0 = (ch + 1) * 32;
            wA0 = *(const float4*)(W + (size_t)(k0 + wr0) * DMM + j0 + wc4);
            wA1 = *(const float4*)(W + (size_t)(k0 + wr0 + 16) * DMM + j0 + wc4);
            xA0 = *(const float4*)(X + (size_t)(m0 + xm0) * DMM + k0 + xkq);
            xA1 = *(const float4*)(X + (size_t)(m0 + xm0 + 32) * DMM + k0 + xkq);
        }
#pragma unroll
        for (int kk = 0; kk < 32; ++kk) {
            const float4 xa = *(const float4*)&Xs[kk][4 * ty];
            const float4 wb = *(const float4*)&Ws[kk][4 * tx];
            acc[0][0] = fmaf(xa.x, wb.x, acc[0][0]); acc[0][1] = fmaf(xa.x, wb.y, acc[0][1]);
            acc[0][2] = fmaf(xa.x, wb.z, acc[0][2]); acc[0][3] = fmaf(xa.x, wb.w, acc[0][3]);
            acc[1][0] = fmaf(xa.y, wb.x, acc[1][0]); acc[1][1] = fmaf(xa.y, wb.y, acc[1][1]);
            acc[1][2] = fmaf(xa.y, wb.z, acc[1][2]); acc[1][3] = fmaf(xa.y, wb.w, acc[1][3]);
            acc[2][0] = fmaf(xa.z, wb.x, acc[2][0]); acc[2][1] = fmaf(xa.z, wb.y, acc[2][1]);
            acc[2][2] = fmaf(xa.z, wb.z, acc[2][2]); acc[2][3] = fmaf(xa.z, wb.w, acc[2][3]);
            acc[3][0] = fmaf(xa.w, wb.x, acc[3][0]); acc[3][1] = fmaf(xa.w, wb.y, acc[3][1]);
            acc[3][2] = fmaf(xa.w, wb.z, acc[3][2]); acc[3][3] = fmaf(xa.w, wb.w, acc[3][3]);
        }
    }

    // epilogue: bias + store to head-major (B,H,L,D). j tile == one head.
    const int h = j0 >> 6;
    const float4 bvv = *(const float4*)(bias + j0 + 4 * tx);
#pragma unroll
    for (int r = 0; r < 4; ++r) {
        const int m = m0 + 4 * ty + r;
        const int b = m >> 11;
        const int l = m & (LL - 1);
        float4 o;
        o.x = acc[r][0] + bvv.x; o.y = acc[r][1] + bvv.y;
        o.z = acc[r][2] + bvv.z; o.w = acc[r][3] + bvv.w;
        *(float4*)(Out + (((size_t)(b * HH + h)) * LL + l) * DD + 4 * tx) = o;
    }
}

// ---------------- K1b: transpose (B,H,L,D) -> (B,H,D,L) ---------------------
__global__ __launch_bounds__(256) void transpose_kernel(const float* __restrict__ src,
                                                        float* __restrict__ dst) {
    __shared__ float tile[64][65];
    const int bh = blockIdx.y;
    const int l0 = blockIdx.x * 64;
    const int d = threadIdx.x & 63;
    const int r0 = threadIdx.x >> 6;
    for (int rr = r0; rr < 64; rr += 4)
        tile[rr][d] = src[((size_t)bh * LL + l0 + rr) * DD + d];
    __syncthreads();
    const int li = threadIdx.x & 63;
    for (int dd = r0; dd < 64; dd += 4)
        dst[((size_t)bh * DD + dd) * LL + l0 + li] = tile[li][dd];
}

// ---------------- K2: measure[b,h,i] = max_j pre - sum_j pre / L ------------
__global__ __launch_bounds__(256) void measure_kernel(const float* __restrict__ qp2,
                                                      const float* __restrict__ kp2,
                                                      const int* __restrict__ rnd,
                                                      float* __restrict__ measure) {
    const int lane = threadIdx.x & 63;
    const int wv = threadIdx.x >> 6;
    const int gq = blockIdx.x * 4 + wv;     // bh*L + i
    const int i = gq & (LL - 1);
    const int bh = gq >> 11;
    const float qv = qp2[((size_t)bh * LL + i) * DD + lane];
    float mx = -INFINITY, tot = 0.f;
    for (int jj = 0; jj < NUMK; ++jj) {
        int idx = rnd[i * NUMK + jj];
        float kv = kp2[((size_t)bh * LL + idx) * DD + lane];
        float p = qv * kv;
#pragma unroll
        for (int off = 32; off > 0; off >>= 1) p += __shfl_xor(p, off, 64);
        mx = fmaxf(mx, p);
        tot += p;
    }
    if (lane == 0) measure[gq] = mx - tot * (1.0f / LL);
}

// ---------------- K3: exact top-40 per (b,h), lax.top_k tie semantics -------
__global__ __launch_bounds__(256) void topk_kernel(const float* __restrict__ measure,
                                                   int* __restrict__ q_idx,
                                                   int* __restrict__ sel_pos) {
    __shared__ float ms[LL];
    __shared__ float wvv[4];
    __shared__ int wvi[4];
    const int t = threadIdx.x;
    const int bh = blockIdx.x;
    for (int i = t; i < LL; i += 256) {
        ms[i] = measure[(size_t)bh * LL + i];
        sel_pos[(size_t)bh * LL + i] = -1;
    }
    __syncthreads();
    for (int it = 0; it < NUMQ; ++it) {
        float bv = -INFINITY; int bi = 0x7fffffff;
        for (int i = t; i < LL; i += 256) {
            float v = ms[i];
            if (v > bv) { bv = v; bi = i; }
        }
#pragma unroll
        for (int off = 32; off > 0; off >>= 1) {
            float ov = __shfl_xor(bv, off, 64);
            int   oi = __shfl_xor(bi, off, 64);
            if (ov > bv || (ov == bv && oi < bi)) { bv = ov; bi = oi; }
        }
        if ((t & 63) == 0) { wvv[t >> 6] = bv; wvi[t >> 6] = bi; }
        __syncthreads();
        if (t == 0) {
            float fv = wvv[0]; int fi = wvi[0];
#pragma unroll
            for (int u = 1; u < 4; ++u)
                if (wvv[u] > fv || (wvv[u] == fv && wvi[u] < fi)) { fv = wvv[u]; fi = wvi[u]; }
            q_idx[bh * NUMQ + it] = fi;
            sel_pos[(size_t)bh * LL + fi] = it;
            ms[fi] = -INFINITY;
        }
        __syncthreads();
    }
}

// ---------------- K4: per (b,h,p): scores -> softmax -> attn out + PV -------
__global__ __launch_bounds__(256) void attn_kernel(const float* __restrict__ qp2,
                                                   const float* __restrict__ kpt,
                                                   const float* __restrict__ vp2,
                                                   const int* __restrict__ q_idx,
                                                   float* __restrict__ attn_out,
                                                   float* __restrict__ out_sel) {
    __shared__ float qs[DD];
    __shared__ float sc[LL];
    __shared__ float reda[4];
    __shared__ float redb[4];
    __shared__ float pvred[16][64];
    const int t = threadIdx.x;
    const int blk = blockIdx.x;           // bh*NUMQ + p
    const int p = blk % NUMQ;
    const int bh = blk / NUMQ;
    const int qi = q_idx[bh * NUMQ + p];
    if (t < DD) qs[t] = qp2[((size_t)bh * LL + qi) * DD + t];
    __syncthreads();

    const float* kbase = kpt + (size_t)bh * DD * LL;
    float4 a0 = make_float4(0.f, 0.f, 0.f, 0.f);
    float4 a1 = make_float4(0.f, 0.f, 0.f, 0.f);
    for (int d = 0; d < DD; ++d) {
        const float qv = qs[d];
        const float4 k0 = *(const float4*)(kbase + (size_t)d * LL + 4 * t);
        const float4 k1 = *(const float4*)(kbase + (size_t)d * LL + 1024 + 4 * t);
        a0.x = fmaf(qv, k0.x, a0.x); a0.y = fmaf(qv, k0.y, a0.y);
        a0.z = fmaf(qv, k0.z, a0.z); a0.w = fmaf(qv, k0.w, a0.w);
        a1.x = fmaf(qv, k1.x, a1.x); a1.y = fmaf(qv, k1.y, a1.y);
        a1.z = fmaf(qv, k1.z, a1.z); a1.w = fmaf(qv, k1.w, a1.w);
    }
    const float scale = 0.125f;
    a0.x *= scale; a0.y *= scale; a0.z *= scale; a0.w *= scale;
    a1.x *= scale; a1.y *= scale; a1.z *= scale; a1.w *= scale;

    float mx = fmaxf(fmaxf(fmaxf(a0.x, a0.y), fmaxf(a0.z, a0.w)),
                     fmaxf(fmaxf(a1.x, a1.y), fmaxf(a1.z, a1.w)));
#pragma unroll
    for (int off = 32; off > 0; off >>= 1) mx = fmaxf(mx, __shfl_xor(mx, off, 64));
    if ((t & 63) == 0) reda[t >> 6] = mx;
    __syncthreads();
    mx = fmaxf(fmaxf(reda[0], reda[1]), fmaxf(reda[2], reda[3]));

    a0.x = __expf(a0.x - mx); a0.y = __expf(a0.y - mx);
    a0.z = __expf(a0.z - mx); a0.w = __expf(a0.w - mx);
    a1.x = __expf(a1.x - mx); a1.y = __expf(a1.y - mx);
    a1.z = __expf(a1.z - mx); a1.w = __expf(a1.w - mx);
    *(float4*)&sc[4 * t] = a0;
    *(float4*)&sc[1024 + 4 * t] = a1;
    float psum = (a0.x + a0.y + a0.z + a0.w) + (a1.x + a1.y + a1.z + a1.w);
#pragma unroll
    for (int off = 32; off > 0; off >>= 1) psum += __shfl_xor(psum, off, 64);
    if ((t & 63) == 0) redb[t >> 6] = psum;
    __syncthreads();
    const float inv = 1.0f / (redb[0] + redb[1] + redb[2] + redb[3]);

    float* arow = attn_out + (size_t)blk * LL;
    float4 w0 = make_float4(a0.x * inv, a0.y * inv, a0.z * inv, a0.w * inv);
    float4 w1 = make_float4(a1.x * inv, a1.y * inv, a1.z * inv, a1.w * inv);
    *(float4*)&arow[4 * t] = w0;
    *(float4*)&arow[1024 + 4 * t] = w1;

    const int dq = (t & 15) * 4;
    const int lg = t >> 4;
    const float* vbase = vp2 + (size_t)bh * LL * DD + dq;
    float4 acc = make_float4(0.f, 0.f, 0.f, 0.f);
    for (int l = lg; l < LL; l += 16) {
        const float pr = sc[l];
        const float4 vv = *(const float4*)(vbase + (size_t)l * DD);
        acc.x = fmaf(pr, vv.x, acc.x); acc.y = fmaf(pr, vv.y, acc.y);
        acc.z = fmaf(pr, vv.z, acc.z); acc.w = fmaf(pr, vv.w, acc.w);
    }
    *(float4*)&pvred[lg][dq] = acc;
    __syncthreads();
    if (t < DD) {
        float s = 0.f;
#pragma unroll
        for (int u = 0; u < 16; ++u) s += pvred[u][t];
        out_sel[((size_t)bh * NUMQ + p) * DD + t] = s * inv;
    }
}

// ---------------- K5: v_mean, two-stage ------------------------------------
__global__ __launch_bounds__(256) void vmean1_kernel(const float* __restrict__ vp2,
                                                     float* __restrict__ partial) {
    __shared__ float pv[256];
    const int t = threadIdx.x;
    const int chunk = blockIdx.x & 31;
    const int bh = blockIdx.x >> 5;
    const int d = t & 63, g = t >> 6;
    const int l0 = chunk * 64;
    float acc = 0.f;
    for (int l = l0 + g; l < l0 + 64; l += 4)
        acc += vp2[((size_t)bh * LL + l) * DD + d];
    pv[t] = acc;
    __syncthreads();
    if (t < 64)
        partial[(size_t)blockIdx.x * 64 + t] = pv[t] + pv[64 + t] + pv[128 + t] + pv[192 + t];
}

__global__ __launch_bounds__(64) void vmean2_kernel(const float* __restrict__ partial,
                                                    float* __restrict__ v_mean) {
    const int bh = blockIdx.x;
    const int t = threadIdx.x;
    float s = 0.f;
    for (int c = 0; c < 32; ++c)
        s += partial[((size_t)bh * 32 + c) * 64 + t];
    v_mean[bh * 64 + t] = s * (1.0f / LL);
}

// ---------------- K6: scatter + residual + LayerNorm ------------------------
__global__ __launch_bounds__(512) void final_kernel(const float* __restrict__ q_in,
                                                    const int* __restrict__ sel_pos,
                                                    const float* __restrict__ out_sel,
                                                    const float* __restrict__ v_mean,
                                                    const float* __restrict__ gamma,
                                                    const float* __restrict__ beta,
                                                    float* __restrict__ yout) {
    __shared__ float wred[8];
    const int j = threadIdx.x;
    const int lane = j & 63, wv = j >> 6;
    const int tok = blockIdx.x;          // b*L + l
    const int b = tok >> 11;
    const int l = tok & (LL - 1);
    const int h = wv, d = lane;          // j = h*64+d since DD=64
    const int bh = b * HH + h;
    const int p = sel_pos[(size_t)bh * LL + l];
    float val = (p >= 0) ? out_sel[((size_t)bh * NUMQ + p) * DD + d]
                         : v_mean[bh * DD + d];
    float y = val + q_in[(size_t)tok * DMM + j];
    float s = y;
#pragma unroll
    for (int off = 32; off > 0; off >>= 1) s += __shfl_xor(s, off, 64);
    if (lane == 0) wred[wv] = s;
    __syncthreads();
    float tot = 0.f;
#pragma unroll
    for (int u = 0; u < 8; ++u) tot += wred[u];
    float mu = tot * (1.0f / DMM);
    __syncthreads();
    float dv = y - mu;
    float s2 = dv * dv;
#pragma unroll
    for (int off = 32; off > 0; off >>= 1) s2 += __shfl_xor(s2, off, 64);
    if (lane == 0) wred[wv] = s2;
    __syncthreads();
    float tot2 = 0.f;
#pragma unroll
    for (int u = 0; u < 8; ++u) tot2 += wred[u];
    float var = tot2 * (1.0f / DMM);
    float yn = dv * rsqrtf(var + LNEPS) * gamma[j] + beta[j];
    yout[(size_t)tok * DMM + j] = yn;
}

extern "C" void kernel_launch(void* const* d_in, const int* in_sizes, int n_in,
                              void* d_out, int out_size, void* d_ws, size_t ws_size,
                              hipStream_t stream) {
    const float* q     = (const float*)d_in[0];
    const float* k     = (const float*)d_in[1];
    const float* v     = (const float*)d_in[2];
    const float* Wq    = (const float*)d_in[3];
    const float* bq    = (const float*)d_in[4];
    const float* Wk    = (const float*)d_in[5];
    const float* bk    = (const float*)d_in[6];
    const float* Wv    = (const float*)d_in[7];
    const float* bv    = (const float*)d_in[8];
    const float* gamma = (const float*)d_in[9];
    const float* beta  = (const float*)d_in[10];
    const int*   rnd   = (const int*)d_in[11];

    float* ws = (float*)d_ws;
    const size_t proj_sz = (size_t)BB * HH * LL * DD;      // = B*L*DM
    float* qp2     = ws;
    float* kp2     = qp2 + proj_sz;
    float* vp2     = kp2 + proj_sz;
    float* kpt     = vp2 + proj_sz;
    float* measure = kpt + proj_sz;                        // B*H*L
    float* out_sel = measure + (size_t)BB * HH * LL;       // B*H*NUMQ*D
    float* v_mean  = out_sel + (size_t)BB * HH * NUMQ * DD;// B*H*D
    float* partial = v_mean + (size_t)BB * HH * DD;        // B*H*32*64
    int*   q_idx   = (int*)(partial + (size_t)BB * HH * 32 * 64);
    int*   sel_pos = q_idx + BB * HH * NUMQ;               // B*H*L

    float* yn_out   = (float*)d_out;
    float* attn_out = yn_out + (size_t)BB * LL * DMM;

    proj_gemm_kernel<<<dim3(BB * LL / 64, DMM / 64, 3), 256, 0, stream>>>(
        q, k, v, Wq, Wk, Wv, bq, bk, bv, qp2, kp2, vp2);
    transpose_kernel<<<dim3(LL / 64, BB * HH), 256, 0, stream>>>(kp2, kpt);
    vmean1_kernel<<<BB * HH * 32, 256, 0, stream>>>(vp2, partial);
    vmean2_kernel<<<BB * HH, 64, 0, stream>>>(partial, v_mean);
    measure_kernel<<<BB * HH * LL / 4, 256, 0, stream>>>(qp2, kp2, rnd, measure);
    topk_kernel<<<BB * HH, 256, 0, stream>>>(measure, q_idx, sel_pos);
    attn_kernel<<<BB * HH * NUMQ, 256, 0, stream>>>(qp2, kpt, vp2, q_idx, attn_out, out_sel);
    final_kernel<<<BB * LL, 512, 0, stream>>>(q, sel_pos, out_sel, v_mean, gamma, beta, yn_out);
}

// Round 4
// 341.805 us; speedup vs baseline: 2.2180x; 1.1121x over previous
//
#include <hip/hip_runtime.h>
#include <math.h>

#define BB 2
#define LL 2048
#define DMM 512
#define HH 8
#define DD 64
#define NUMK 40
#define NUMQ 40
#define LNEPS 1e-5f

typedef unsigned short ushort_t;
typedef __attribute__((ext_vector_type(8))) short bf16x8;
typedef __attribute__((ext_vector_type(4))) float f32x4;

// ---- bf16 helpers (RNE) ----
__device__ inline ushort_t f2bf(float x) {
    union { float f; unsigned int u; } v; v.f = x;
    unsigned int r = v.u + 0x7fffu + ((v.u >> 16) & 1u);
    return (ushort_t)(r >> 16);
}
__device__ inline float bf2f(ushort_t h) {
    union { unsigned int u; float f; } v; v.u = ((unsigned int)h) << 16;
    return v.f;
}

// ---------------- K0a: convert X (q,k,v) -> hi/lo bf16 ----------------------
__global__ __launch_bounds__(256) void convert_x_kernel(
    const float* __restrict__ q, const float* __restrict__ k, const float* __restrict__ v,
    ushort_t* __restrict__ Xh, ushort_t* __restrict__ Xl) {
    const size_t plane = (size_t)BB * LL * DMM;
    const float* X = (blockIdx.y == 0) ? q : (blockIdx.y == 1) ? k : v;
    ushort_t* xh = Xh + plane * blockIdx.y;
    ushort_t* xl = Xl + plane * blockIdx.y;
    const size_t base = ((size_t)blockIdx.x * 256 + threadIdx.x) * 8;
    float4 a = *(const float4*)(X + base);
    float4 b = *(const float4*)(X + base + 4);
    float xs[8] = {a.x, a.y, a.z, a.w, b.x, b.y, b.z, b.w};
    unsigned int hp[4], lp[4];
#pragma unroll
    for (int j = 0; j < 4; ++j) {
        ushort_t h0 = f2bf(xs[2 * j]),     h1 = f2bf(xs[2 * j + 1]);
        ushort_t l0 = f2bf(xs[2 * j] - bf2f(h0));
        ushort_t l1 = f2bf(xs[2 * j + 1] - bf2f(h1));
        hp[j] = (unsigned int)h0 | ((unsigned int)h1 << 16);
        lp[j] = (unsigned int)l0 | ((unsigned int)l1 << 16);
    }
    *(uint4*)(xh + base) = make_uint4(hp[0], hp[1], hp[2], hp[3]);
    *(uint4*)(xl + base) = make_uint4(lp[0], lp[1], lp[2], lp[3]);
}

// ---------------- K0b: convert + transpose W -> Wt[n][k] hi/lo bf16 ---------
__global__ __launch_bounds__(256) void convert_w_kernel(
    const float* __restrict__ Wq, const float* __restrict__ Wk, const float* __restrict__ Wv,
    ushort_t* __restrict__ Wht, ushort_t* __restrict__ Wlt) {
    __shared__ float tile[64][65];
    const size_t plane = (size_t)DMM * DMM;
    const float* W = (blockIdx.z == 0) ? Wq : (blockIdx.z == 1) ? Wk : Wv;
    ushort_t* wht = Wht + plane * blockIdx.z;
    ushort_t* wlt = Wlt + plane * blockIdx.z;
    const int n0 = blockIdx.x * 64, k0 = blockIdx.y * 64;
    const int t = threadIdx.x;
    const int d = t & 63, g = t >> 6;
    for (int rr = g; rr < 64; rr += 4)
        tile[rr][d] = W[(size_t)(k0 + rr) * DMM + n0 + d];
    __syncthreads();
    for (int cc = g; cc < 64; cc += 4) {
        float x = tile[d][cc];            // = W[k0+d][n0+cc]
        ushort_t hi = f2bf(x);
        ushort_t lo = f2bf(x - bf2f(hi));
        wht[(size_t)(n0 + cc) * DMM + k0 + d] = hi;
        wlt[(size_t)(n0 + cc) * DMM + k0 + d] = lo;
    }
}

// ---------------- K1: split-bf16 MFMA projection GEMM -----------------------
// grid (M/64, N/64, 3); block 256 (4 waves, each 32x32). BK=64.
// LDS tiles stored as XOR-swizzled 16B chunks: global chunk (r,c) at idx r*8+(c^(r&7)).
__device__ inline void stage_one(const ushort_t* __restrict__ g, ushort_t* lbuf,
                                 int r0, int lane, int k0) {
    const int r = r0 + (lane >> 3);
    const int c = (lane & 7) ^ (r & 7);
    const ushort_t* gp = g + (size_t)r * DMM + k0 + c * 8;
    __builtin_amdgcn_global_load_lds(
        (const __attribute__((address_space(1))) unsigned int*)gp,
        (__attribute__((address_space(3))) unsigned int*)(lbuf + (size_t)r0 * 64),
        16, 0, 0);
}
__device__ inline bf16x8 frag_ld(const ushort_t* buf, int row, int c) {
    const int idx = row * 8 + (c ^ (row & 7));
    return *(const bf16x8*)(buf + idx * 8);
}

__global__ __launch_bounds__(256) void proj_mfma_kernel(
    const ushort_t* __restrict__ Xh, const ushort_t* __restrict__ Xl,
    const ushort_t* __restrict__ Wht, const ushort_t* __restrict__ Wlt,
    const float* __restrict__ bq, const float* __restrict__ bk, const float* __restrict__ bv,
    float* __restrict__ Oq, float* __restrict__ Ok, float* __restrict__ Ov) {
    const int z = blockIdx.z;
    const size_t xplane = (size_t)BB * LL * DMM;
    const size_t wplane = (size_t)DMM * DMM;
    const ushort_t* ah_g = Xh + xplane * z;
    const ushort_t* al_g = Xl + xplane * z;
    const ushort_t* bh_g = Wht + wplane * z;
    const ushort_t* bl_g = Wlt + wplane * z;
    const float* bias = (z == 0) ? bq : (z == 1) ? bk : bv;
    float* Out = (z == 0) ? Oq : (z == 1) ? Ok : Ov;

    __shared__ __align__(16) ushort_t bufAh[64 * 64];
    __shared__ __align__(16) ushort_t bufAl[64 * 64];
    __shared__ __align__(16) ushort_t bufBh[64 * 64];
    __shared__ __align__(16) ushort_t bufBl[64 * 64];

    const int t = threadIdx.x;
    const int lane = t & 63, w = t >> 6;
    const int wm = (w & 1) * 32, wn = (w >> 1) * 32;
    const int m0 = blockIdx.x * 64, j0 = blockIdx.y * 64;

    const ushort_t* A_h = ah_g + (size_t)m0 * DMM;
    const ushort_t* A_l = al_g + (size_t)m0 * DMM;
    const ushort_t* B_h = bh_g + (size_t)j0 * DMM;
    const ushort_t* B_l = bl_g + (size_t)j0 * DMM;

    f32x4 acc[2][2];
#pragma unroll
    for (int i = 0; i < 2; ++i)
#pragma unroll
        for (int j = 0; j < 2; ++j) acc[i][j] = (f32x4){0.f, 0.f, 0.f, 0.f};

    for (int ch = 0; ch < 8; ++ch) {
        const int k0 = ch * 64;
#pragma unroll
        for (int i = 0; i < 2; ++i) {
            const int r0 = (w * 2 + i) * 8;
            stage_one(A_h, bufAh, r0, lane, k0);
            stage_one(A_l, bufAl, r0, lane, k0);
            stage_one(B_h, bufBh, r0, lane, k0);
            stage_one(B_l, bufBl, r0, lane, k0);
        }
        __syncthreads();
#pragma unroll
        for (int ks = 0; ks < 2; ++ks) {
            const int cc = ks * 4 + (lane >> 4);
            bf16x8 fah[2], fal[2], fbh[2], fbl[2];
#pragma unroll
            for (int tm = 0; tm < 2; ++tm) {
                const int row = wm + tm * 16 + (lane & 15);
                fah[tm] = frag_ld(bufAh, row, cc);
                fal[tm] = frag_ld(bufAl, row, cc);
            }
#pragma unroll
            for (int tn = 0; tn < 2; ++tn) {
                const int row = wn + tn * 16 + (lane & 15);
                fbh[tn] = frag_ld(bufBh, row, cc);
                fbl[tn] = frag_ld(bufBl, row, cc);
            }
#pragma unroll
            for (int tm = 0; tm < 2; ++tm)
#pragma unroll
                for (int tn = 0; tn < 2; ++tn) {
                    acc[tm][tn] = __builtin_amdgcn_mfma_f32_16x16x32_bf16(fah[tm], fbh[tn], acc[tm][tn], 0, 0, 0);
                    acc[tm][tn] = __builtin_amdgcn_mfma_f32_16x16x32_bf16(fal[tm], fbh[tn], acc[tm][tn], 0, 0, 0);
                    acc[tm][tn] = __builtin_amdgcn_mfma_f32_16x16x32_bf16(fah[tm], fbl[tn], acc[tm][tn], 0, 0, 0);
                    acc[tm][tn] = __builtin_amdgcn_mfma_f32_16x16x32_bf16(fal[tm], fbl[tn], acc[tm][tn], 0, 0, 0);
                }
        }
        __syncthreads();
    }

    // epilogue: C/D layout col=lane&15, row=(lane>>4)*4+reg; write head-major (B,H,L,D)
#pragma unroll
    for (int tn = 0; tn < 2; ++tn) {
        const int gn = j0 + wn + tn * 16 + (lane & 15);
        const float bvv = bias[gn];
        const int h = gn >> 6, d = gn & 63;
#pragma unroll
        for (int tm = 0; tm < 2; ++tm) {
#pragma unroll
            for (int reg = 0; reg < 4; ++reg) {
                const int gm = m0 + wm + tm * 16 + (lane >> 4) * 4 + reg;
                const int b = gm >> 11, l = gm & (LL - 1);
                Out[(((size_t)(b * HH + h)) * LL + l) * DD + d] = acc[tm][tn][reg] + bvv;
            }
        }
    }
}

// ---------------- K1b: transpose (B,H,L,D) -> (B,H,D,L) ---------------------
__global__ __launch_bounds__(256) void transpose_kernel(const float* __restrict__ src,
                                                        float* __restrict__ dst) {
    __shared__ float tile[64][65];
    const int bh = blockIdx.y;
    const int l0 = blockIdx.x * 64;
    const int d = threadIdx.x & 63;
    const int r0 = threadIdx.x >> 6;
    for (int rr = r0; rr < 64; rr += 4)
        tile[rr][d] = src[((size_t)bh * LL + l0 + rr) * DD + d];
    __syncthreads();
    const int li = threadIdx.x & 63;
    for (int dd = r0; dd < 64; dd += 4)
        dst[((size_t)bh * DD + dd) * LL + l0 + li] = tile[li][dd];
}

// ---------------- K2: measure[b,h,i] = max_j pre - sum_j pre / L ------------
__global__ __launch_bounds__(256) void measure_kernel(const float* __restrict__ qp2,
                                                      const float* __restrict__ kp2,
                                                      const int* __restrict__ rnd,
                                                      float* __restrict__ measure) {
    const int lane = threadIdx.x & 63;
    const int wv = threadIdx.x >> 6;
    const int gq = blockIdx.x * 4 + wv;     // bh*L + i
    const int i = gq & (LL - 1);
    const int bh = gq >> 11;
    const float qv = qp2[((size_t)bh * LL + i) * DD + lane];
    float mx = -INFINITY, tot = 0.f;
    for (int jj = 0; jj < NUMK; ++jj) {
        int idx = rnd[i * NUMK + jj];
        float kv = kp2[((size_t)bh * LL + idx) * DD + lane];
        float p = qv * kv;
#pragma unroll
        for (int off = 32; off > 0; off >>= 1) p += __shfl_xor(p, off, 64);
        mx = fmaxf(mx, p);
        tot += p;
    }
    if (lane == 0) measure[gq] = mx - tot * (1.0f / LL);
}

// ---------------- K3: exact top-40 per (b,h), lax.top_k tie semantics -------
__global__ __launch_bounds__(256) void topk_kernel(const float* __restrict__ measure,
                                                   int* __restrict__ q_idx,
                                                   int* __restrict__ sel_pos) {
    __shared__ float ms[LL];
    __shared__ float wvv[4];
    __shared__ int wvi[4];
    const int t = threadIdx.x;
    const int bh = blockIdx.x;
    for (int i = t; i < LL; i += 256) {
        ms[i] = measure[(size_t)bh * LL + i];
        sel_pos[(size_t)bh * LL + i] = -1;
    }
    __syncthreads();
    for (int it = 0; it < NUMQ; ++it) {
        float bv = -INFINITY; int bi = 0x7fffffff;
        for (int i = t; i < LL; i += 256) {
            float v = ms[i];
            if (v > bv) { bv = v; bi = i; }
        }
#pragma unroll
        for (int off = 32; off > 0; off >>= 1) {
            float ov = __shfl_xor(bv, off, 64);
            int   oi = __shfl_xor(bi, off, 64);
            if (ov > bv || (ov == bv && oi < bi)) { bv = ov; bi = oi; }
        }
        if ((t & 63) == 0) { wvv[t >> 6] = bv; wvi[t >> 6] = bi; }
        __syncthreads();
        if (t == 0) {
            float fv = wvv[0]; int fi = wvi[0];
#pragma unroll
            for (int u = 1; u < 4; ++u)
                if (wvv[u] > fv || (wvv[u] == fv && wvi[u] < fi)) { fv = wvv[u]; fi = wvi[u]; }
            q_idx[bh * NUMQ + it] = fi;
            sel_pos[(size_t)bh * LL + fi] = it;
            ms[fi] = -INFINITY;
        }
        __syncthreads();
    }
}

// ---------------- K4: per (b,h,p): scores -> softmax -> attn out + PV -------
__global__ __launch_bounds__(256) void attn_kernel(const float* __restrict__ qp2,
                                                   const float* __restrict__ kpt,
                                                   const float* __restrict__ vp2,
                                                   const int* __restrict__ q_idx,
                                                   float* __restrict__ attn_out,
                                                   float* __restrict__ out_sel) {
    __shared__ float qs[DD];
    __shared__ float sc[LL];
    __shared__ float reda[4];
    __shared__ float redb[4];
    __shared__ float pvred[16][64];
    const int t = threadIdx.x;
    const int blk = blockIdx.x;           // bh*NUMQ + p
    const int p = blk % NUMQ;
    const int bh = blk / NUMQ;
    const int qi = q_idx[bh * NUMQ + p];
    if (t < DD) qs[t] = qp2[((size_t)bh * LL + qi) * DD + t];
    __syncthreads();

    const float* kbase = kpt + (size_t)bh * DD * LL;
    float4 a0 = make_float4(0.f, 0.f, 0.f, 0.f);
    float4 a1 = make_float4(0.f, 0.f, 0.f, 0.f);
    for (int d = 0; d < DD; ++d) {
        const float qv = qs[d];
        const float4 k0 = *(const float4*)(kbase + (size_t)d * LL + 4 * t);
        const float4 k1 = *(const float4*)(kbase + (size_t)d * LL + 1024 + 4 * t);
        a0.x = fmaf(qv, k0.x, a0.x); a0.y = fmaf(qv, k0.y, a0.y);
        a0.z = fmaf(qv, k0.z, a0.z); a0.w = fmaf(qv, k0.w, a0.w);
        a1.x = fmaf(qv, k1.x, a1.x); a1.y = fmaf(qv, k1.y, a1.y);
        a1.z = fmaf(qv, k1.z, a1.z); a1.w = fmaf(qv, k1.w, a1.w);
    }
    const float scale = 0.125f;
    a0.x *= scale; a0.y *= scale; a0.z *= scale; a0.w *= scale;
    a1.x *= scale; a1.y *= scale; a1.z *= scale; a1.w *= scale;

    float mx = fmaxf(fmaxf(fmaxf(a0.x, a0.y), fmaxf(a0.z, a0.w)),
                     fmaxf(fmaxf(a1.x, a1.y), fmaxf(a1.z, a1.w)));
#pragma unroll
    for (int off = 32; off > 0; off >>= 1) mx = fmaxf(mx, __shfl_xor(mx, off, 64));
    if ((t & 63) == 0) reda[t >> 6] = mx;
    __syncthreads();
    mx = fmaxf(fmaxf(reda[0], reda[1]), fmaxf(reda[2], reda[3]));

    a0.x = __expf(a0.x - mx); a0.y = __expf(a0.y - mx);
    a0.z = __expf(a0.z - mx); a0.w = __expf(a0.w - mx);
    a1.x = __expf(a1.x - mx); a1.y = __expf(a1.y - mx);
    a1.z = __expf(a1.z - mx); a1.w = __expf(a1.w - mx);
    *(float4*)&sc[4 * t] = a0;
    *(float4*)&sc[1024 + 4 * t] = a1;
    float psum = (a0.x + a0.y + a0.z + a0.w) + (a1.x + a1.y + a1.z + a1.w);
#pragma unroll
    for (int off = 32; off > 0; off >>= 1) psum += __shfl_xor(psum, off, 64);
    if ((t & 63) == 0) redb[t >> 6] = psum;
    __syncthreads();
    const float inv = 1.0f / (redb[0] + redb[1] + redb[2] + redb[3]);

    float* arow = attn_out + (size_t)blk * LL;
    float4 w0 = make_float4(a0.x * inv, a0.y * inv, a0.z * inv, a0.w * inv);
    float4 w1 = make_float4(a1.x * inv, a1.y * inv, a1.z * inv, a1.w * inv);
    *(float4*)&arow[4 * t] = w0;
    *(float4*)&arow[1024 + 4 * t] = w1;

    const int dq = (t & 15) * 4;
    const int lg = t >> 4;
    const float* vbase = vp2 + (size_t)bh * LL * DD + dq;
    float4 acc = make_float4(0.f, 0.f, 0.f, 0.f);
    for (int l = lg; l < LL; l += 16) {
        const float pr = sc[l];
        const float4 vv = *(const float4*)(vbase + (size_t)l * DD);
        acc.x = fmaf(pr, vv.x, acc.x); acc.y = fmaf(pr, vv.y, acc.y);
        acc.z = fmaf(pr, vv.z, acc.z); acc.w = fmaf(pr, vv.w, acc.w);
    }
    *(float4*)&pvred[lg][dq] = acc;
    __syncthreads();
    if (t < DD) {
        float s = 0.f;
#pragma unroll
        for (int u = 0; u < 16; ++u) s += pvred[u][t];
        out_sel[((size_t)bh * NUMQ + p) * DD + t] = s * inv;
    }
}

// ---------------- K5: v_mean, two-stage ------------------------------------
__global__ __launch_bounds__(256) void vmean1_kernel(const float* __restrict__ vp2,
                                                     float* __restrict__ partial) {
    __shared__ float pv[256];
    const int t = threadIdx.x;
    const int chunk = blockIdx.x & 31;
    const int bh = blockIdx.x >> 5;
    const int d = t & 63, g = t >> 6;
    const int l0 = chunk * 64;
    float acc = 0.f;
    for (int l = l0 + g; l < l0 + 64; l += 4)
        acc += vp2[((size_t)bh * LL + l) * DD + d];
    pv[t] = acc;
    __syncthreads();
    if (t < 64)
        partial[(size_t)blockIdx.x * 64 + t] = pv[t] + pv[64 + t] + pv[128 + t] + pv[192 + t];
}

__global__ __launch_bounds__(64) void vmean2_kernel(const float* __restrict__ partial,
                                                    float* __restrict__ v_mean) {
    const int bh = blockIdx.x;
    const int t = threadIdx.x;
    float s = 0.f;
    for (int c = 0; c < 32; ++c)
        s += partial[((size_t)bh * 32 + c) * 64 + t];
    v_mean[bh * 64 + t] = s * (1.0f / LL);
}

// ---------------- K6: scatter + residual + LayerNorm ------------------------
__global__ __launch_bounds__(512) void final_kernel(const float* __restrict__ q_in,
                                                    const int* __restrict__ sel_pos,
                                                    const float* __restrict__ out_sel,
                                                    const float* __restrict__ v_mean,
                                                    const float* __restrict__ gamma,
                                                    const float* __restrict__ beta,
                                                    float* __restrict__ yout) {
    __shared__ float wred[8];
    const int j = threadIdx.x;
    const int lane = j & 63, wv = j >> 6;
    const int tok = blockIdx.x;          // b*L + l
    const int b = tok >> 11;
    const int l = tok & (LL - 1);
    const int h = wv, d = lane;          // j = h*64+d since DD=64
    const int bh = b * HH + h;
    const int p = sel_pos[(size_t)bh * LL + l];
    float val = (p >= 0) ? out_sel[((size_t)bh * NUMQ + p) * DD + d]
                         : v_mean[bh * DD + d];
    float y = val + q_in[(size_t)tok * DMM + j];
    float s = y;
#pragma unroll
    for (int off = 32; off > 0; off >>= 1) s += __shfl_xor(s, off, 64);
    if (lane == 0) wred[wv] = s;
    __syncthreads();
    float tot = 0.f;
#pragma unroll
    for (int u = 0; u < 8; ++u) tot += wred[u];
    float mu = tot * (1.0f / DMM);
    __syncthreads();
    float dv = y - mu;
    float s2 = dv * dv;
#pragma unroll
    for (int off = 32; off > 0; off >>= 1) s2 += __shfl_xor(s2, off, 64);
    if (lane == 0) wred[wv] = s2;
    __syncthreads();
    float tot2 = 0.f;
#pragma unroll
    for (int u = 0; u < 8; ++u) tot2 += wred[u];
    float var = tot2 * (1.0f / DMM);
    float yn = dv * rsqrtf(var + LNEPS) * gamma[j] + beta[j];
    yout[(size_t)tok * DMM + j] = yn;
}

extern "C" void kernel_launch(void* const* d_in, const int* in_sizes, int n_in,
                              void* d_out, int out_size, void* d_ws, size_t ws_size,
                              hipStream_t stream) {
    const float* q     = (const float*)d_in[0];
    const float* k     = (const float*)d_in[1];
    const float* v     = (const float*)d_in[2];
    const float* Wq    = (const float*)d_in[3];
    const float* bq    = (const float*)d_in[4];
    const float* Wk    = (const float*)d_in[5];
    const float* bk    = (const float*)d_in[6];
    const float* Wv    = (const float*)d_in[7];
    const float* bv    = (const float*)d_in[8];
    const float* gamma = (const float*)d_in[9];
    const float* beta  = (const float*)d_in[10];
    const int*   rnd   = (const int*)d_in[11];

    float* ws = (float*)d_ws;
    const size_t proj_sz = (size_t)BB * HH * LL * DD;      // = B*L*DM elements
    float* qp2     = ws;
    float* kp2     = qp2 + proj_sz;
    float* vp2     = kp2 + proj_sz;
    float* kpt     = vp2 + proj_sz;
    float* measure = kpt + proj_sz;                        // B*H*L
    float* out_sel = measure + (size_t)BB * HH * LL;       // B*H*NUMQ*D
    float* v_mean  = out_sel + (size_t)BB * HH * NUMQ * DD;// B*H*D
    float* partial = v_mean + (size_t)BB * HH * DD;        // B*H*32*64
    int*   q_idx   = (int*)(partial + (size_t)BB * HH * 32 * 64);
    int*   sel_pos = q_idx + BB * HH * NUMQ;               // B*H*L
    // bf16 split buffers (ushort): after sel_pos
    ushort_t* Xh  = (ushort_t*)(sel_pos + BB * HH * LL);
    ushort_t* Xl  = Xh + 3 * proj_sz;
    ushort_t* Wht = Xl + 3 * proj_sz;
    ushort_t* Wlt = Wht + 3 * (size_t)DMM * DMM;

    float* yn_out   = (float*)d_out;
    float* attn_out = yn_out + (size_t)BB * LL * DMM;

    convert_x_kernel<<<dim3(BB * LL * DMM / (256 * 8), 3), 256, 0, stream>>>(q, k, v, Xh, Xl);
    convert_w_kernel<<<dim3(DMM / 64, DMM / 64, 3), 256, 0, stream>>>(Wq, Wk, Wv, Wht, Wlt);
    proj_mfma_kernel<<<dim3(BB * LL / 64, DMM / 64, 3), 256, 0, stream>>>(
        Xh, Xl, Wht, Wlt, bq, bk, bv, qp2, kp2, vp2);
    transpose_kernel<<<dim3(LL / 64, BB * HH), 256, 0, stream>>>(kp2, kpt);
    vmean1_kernel<<<BB * HH * 32, 256, 0, stream>>>(vp2, partial);
    vmean2_kernel<<<BB * HH, 64, 0, stream>>>(partial, v_mean);
    measure_kernel<<<BB * HH * LL / 4, 256, 0, stream>>>(qp2, kp2, rnd, measure);
    topk_kernel<<<BB * HH, 256, 0, stream>>>(measure, q_idx, sel_pos);
    attn_kernel<<<BB * HH * NUMQ, 256, 0, stream>>>(qp2, kpt, vp2, q_idx, attn_out, out_sel);
    final_kernel<<<BB * LL, 512, 0, stream>>>(q, sel_pos, out_sel, v_mean, gamma, beta, yn_out);
}

// Round 5
// 258.375 us; speedup vs baseline: 2.9342x; 1.3229x over previous
//
#include <hip/hip_runtime.h>
#include <math.h>

#define BB 2
#define LL 2048
#define DMM 512
#define HH 8
#define DD 64
#define NUMK 40
#define NUMQ 40
#define LNEPS 1e-5f

typedef unsigned short ushort_t;
typedef __attribute__((ext_vector_type(8))) short bf16x8;
typedef __attribute__((ext_vector_type(4))) float f32x4;

// ---- bf16 helpers (RNE) ----
__device__ inline ushort_t f2bf(float x) {
    union { float f; unsigned int u; } v; v.f = x;
    unsigned int r = v.u + 0x7fffu + ((v.u >> 16) & 1u);
    return (ushort_t)(r >> 16);
}
__device__ inline float bf2f(ushort_t h) {
    union { unsigned int u; float f; } v; v.u = ((unsigned int)h) << 16;
    return v.f;
}

// ---------------- K0a: convert X (q,k,v) -> hi/lo bf16 ----------------------
__global__ __launch_bounds__(256) void convert_x_kernel(
    const float* __restrict__ q, const float* __restrict__ k, const float* __restrict__ v,
    ushort_t* __restrict__ Xh, ushort_t* __restrict__ Xl) {
    const size_t plane = (size_t)BB * LL * DMM;
    const float* X = (blockIdx.y == 0) ? q : (blockIdx.y == 1) ? k : v;
    ushort_t* xh = Xh + plane * blockIdx.y;
    ushort_t* xl = Xl + plane * blockIdx.y;
    const size_t base = ((size_t)blockIdx.x * 256 + threadIdx.x) * 8;
    float4 a = *(const float4*)(X + base);
    float4 b = *(const float4*)(X + base + 4);
    float xs[8] = {a.x, a.y, a.z, a.w, b.x, b.y, b.z, b.w};
    unsigned int hp[4], lp[4];
#pragma unroll
    for (int j = 0; j < 4; ++j) {
        ushort_t h0 = f2bf(xs[2 * j]),     h1 = f2bf(xs[2 * j + 1]);
        ushort_t l0 = f2bf(xs[2 * j] - bf2f(h0));
        ushort_t l1 = f2bf(xs[2 * j + 1] - bf2f(h1));
        hp[j] = (unsigned int)h0 | ((unsigned int)h1 << 16);
        lp[j] = (unsigned int)l0 | ((unsigned int)l1 << 16);
    }
    *(uint4*)(xh + base) = make_uint4(hp[0], hp[1], hp[2], hp[3]);
    *(uint4*)(xl + base) = make_uint4(lp[0], lp[1], lp[2], lp[3]);
}

// ---------------- K0b: convert + transpose W -> Wt[n][k] hi/lo bf16 ---------
__global__ __launch_bounds__(256) void convert_w_kernel(
    const float* __restrict__ Wq, const float* __restrict__ Wk, const float* __restrict__ Wv,
    ushort_t* __restrict__ Wht, ushort_t* __restrict__ Wlt) {
    __shared__ float tile[64][65];
    const size_t plane = (size_t)DMM * DMM;
    const float* W = (blockIdx.z == 0) ? Wq : (blockIdx.z == 1) ? Wk : Wv;
    ushort_t* wht = Wht + plane * blockIdx.z;
    ushort_t* wlt = Wlt + plane * blockIdx.z;
    const int n0 = blockIdx.x * 64, k0 = blockIdx.y * 64;
    const int t = threadIdx.x;
    const int d = t & 63, g = t >> 6;
    for (int rr = g; rr < 64; rr += 4)
        tile[rr][d] = W[(size_t)(k0 + rr) * DMM + n0 + d];
    __syncthreads();
    for (int cc = g; cc < 64; cc += 4) {
        float x = tile[d][cc];            // = W[k0+d][n0+cc]
        ushort_t hi = f2bf(x);
        ushort_t lo = f2bf(x - bf2f(hi));
        wht[(size_t)(n0 + cc) * DMM + k0 + d] = hi;
        wlt[(size_t)(n0 + cc) * DMM + k0 + d] = lo;
    }
}

// ---------------- K1: split-bf16 MFMA projection GEMM -----------------------
__device__ inline void stage_one(const ushort_t* __restrict__ g, ushort_t* lbuf,
                                 int r0, int lane, int k0) {
    const int r = r0 + (lane >> 3);
    const int c = (lane & 7) ^ (r & 7);
    const ushort_t* gp = g + (size_t)r * DMM + k0 + c * 8;
    __builtin_amdgcn_global_load_lds(
        (const __attribute__((address_space(1))) unsigned int*)gp,
        (__attribute__((address_space(3))) unsigned int*)(lbuf + (size_t)r0 * 64),
        16, 0, 0);
}
__device__ inline bf16x8 frag_ld(const ushort_t* buf, int row, int c) {
    const int idx = row * 8 + (c ^ (row & 7));
    return *(const bf16x8*)(buf + idx * 8);
}

__global__ __launch_bounds__(256) void proj_mfma_kernel(
    const ushort_t* __restrict__ Xh, const ushort_t* __restrict__ Xl,
    const ushort_t* __restrict__ Wht, const ushort_t* __restrict__ Wlt,
    const float* __restrict__ bq, const float* __restrict__ bk, const float* __restrict__ bv,
    float* __restrict__ Oq, float* __restrict__ Ok, float* __restrict__ Ov) {
    const int z = blockIdx.z;
    const size_t xplane = (size_t)BB * LL * DMM;
    const size_t wplane = (size_t)DMM * DMM;
    const ushort_t* ah_g = Xh + xplane * z;
    const ushort_t* al_g = Xl + xplane * z;
    const ushort_t* bh_g = Wht + wplane * z;
    const ushort_t* bl_g = Wlt + wplane * z;
    const float* bias = (z == 0) ? bq : (z == 1) ? bk : bv;
    float* Out = (z == 0) ? Oq : (z == 1) ? Ok : Ov;

    __shared__ __align__(16) ushort_t bufAh[64 * 64];
    __shared__ __align__(16) ushort_t bufAl[64 * 64];
    __shared__ __align__(16) ushort_t bufBh[64 * 64];
    __shared__ __align__(16) ushort_t bufBl[64 * 64];

    const int t = threadIdx.x;
    const int lane = t & 63, w = t >> 6;
    const int wm = (w & 1) * 32, wn = (w >> 1) * 32;
    const int m0 = blockIdx.x * 64, j0 = blockIdx.y * 64;

    const ushort_t* A_h = ah_g + (size_t)m0 * DMM;
    const ushort_t* A_l = al_g + (size_t)m0 * DMM;
    const ushort_t* B_h = bh_g + (size_t)j0 * DMM;
    const ushort_t* B_l = bl_g + (size_t)j0 * DMM;

    f32x4 acc[2][2];
#pragma unroll
    for (int i = 0; i < 2; ++i)
#pragma unroll
        for (int j = 0; j < 2; ++j) acc[i][j] = (f32x4){0.f, 0.f, 0.f, 0.f};

    for (int ch = 0; ch < 8; ++ch) {
        const int k0 = ch * 64;
#pragma unroll
        for (int i = 0; i < 2; ++i) {
            const int r0 = (w * 2 + i) * 8;
            stage_one(A_h, bufAh, r0, lane, k0);
            stage_one(A_l, bufAl, r0, lane, k0);
            stage_one(B_h, bufBh, r0, lane, k0);
            stage_one(B_l, bufBl, r0, lane, k0);
        }
        __syncthreads();
#pragma unroll
        for (int ks = 0; ks < 2; ++ks) {
            const int cc = ks * 4 + (lane >> 4);
            bf16x8 fah[2], fal[2], fbh[2], fbl[2];
#pragma unroll
            for (int tm = 0; tm < 2; ++tm) {
                const int row = wm + tm * 16 + (lane & 15);
                fah[tm] = frag_ld(bufAh, row, cc);
                fal[tm] = frag_ld(bufAl, row, cc);
            }
#pragma unroll
            for (int tn = 0; tn < 2; ++tn) {
                const int row = wn + tn * 16 + (lane & 15);
                fbh[tn] = frag_ld(bufBh, row, cc);
                fbl[tn] = frag_ld(bufBl, row, cc);
            }
#pragma unroll
            for (int tm = 0; tm < 2; ++tm)
#pragma unroll
                for (int tn = 0; tn < 2; ++tn) {
                    acc[tm][tn] = __builtin_amdgcn_mfma_f32_16x16x32_bf16(fah[tm], fbh[tn], acc[tm][tn], 0, 0, 0);
                    acc[tm][tn] = __builtin_amdgcn_mfma_f32_16x16x32_bf16(fal[tm], fbh[tn], acc[tm][tn], 0, 0, 0);
                    acc[tm][tn] = __builtin_amdgcn_mfma_f32_16x16x32_bf16(fah[tm], fbl[tn], acc[tm][tn], 0, 0, 0);
                    acc[tm][tn] = __builtin_amdgcn_mfma_f32_16x16x32_bf16(fal[tm], fbl[tn], acc[tm][tn], 0, 0, 0);
                }
        }
        __syncthreads();
    }

#pragma unroll
    for (int tn = 0; tn < 2; ++tn) {
        const int gn = j0 + wn + tn * 16 + (lane & 15);
        const float bvv = bias[gn];
        const int h = gn >> 6, d = gn & 63;
#pragma unroll
        for (int tm = 0; tm < 2; ++tm) {
#pragma unroll
            for (int reg = 0; reg < 4; ++reg) {
                const int gm = m0 + wm + tm * 16 + (lane >> 4) * 4 + reg;
                const int b = gm >> 11, l = gm & (LL - 1);
                Out[(((size_t)(b * HH + h)) * LL + l) * DD + d] = acc[tm][tn][reg] + bvv;
            }
        }
    }
}

// ---------------- K1b: transpose (B,H,L,D) -> (B,H,D,L) ---------------------
__global__ __launch_bounds__(256) void transpose_kernel(const float* __restrict__ src,
                                                        float* __restrict__ dst) {
    __shared__ float tile[64][65];
    const int bh = blockIdx.y;
    const int l0 = blockIdx.x * 64;
    const int d = threadIdx.x & 63;
    const int r0 = threadIdx.x >> 6;
    for (int rr = r0; rr < 64; rr += 4)
        tile[rr][d] = src[((size_t)bh * LL + l0 + rr) * DD + d];
    __syncthreads();
    const int li = threadIdx.x & 63;
    for (int dd = r0; dd < 64; dd += 4)
        dst[((size_t)bh * DD + dd) * LL + l0 + li] = tile[li][dd];
}

// ---------------- K2: measure v2 — 4 queries/wave, 16 lanes each ------------
// grid (16, 128): x = bh (XCD-local), y = query group of 16.
__global__ __launch_bounds__(256) void measure_kernel(const float* __restrict__ qp2,
                                                      const float* __restrict__ kp2,
                                                      const int* __restrict__ rnd,
                                                      float* __restrict__ measure) {
    const int t = threadIdx.x;
    const int lane = t & 63;
    const int wv = t >> 6;
    const int g = lane >> 4;          // query subgroup 0..3
    const int dq = (lane & 15) * 4;   // d quad
    const int bh = blockIdx.x;
    const int i = blockIdx.y * 16 + wv * 4 + g;
    const float4 qv = *(const float4*)(qp2 + ((size_t)bh * LL + i) * DD + dq);
    const float* kbase = kp2 + (size_t)bh * LL * DD;
    const int* rp = rnd + i * NUMK;
    float mx = -INFINITY, sm = 0.f;
#pragma unroll 8
    for (int j = 0; j < NUMK; ++j) {
        const int row = rp[j];
        const float4 kv = *(const float4*)(kbase + (size_t)row * DD + dq);
        float p = kv.x * qv.x;
        p = fmaf(kv.y, qv.y, p); p = fmaf(kv.z, qv.z, p); p = fmaf(kv.w, qv.w, p);
        p += __shfl_xor(p, 1, 64);
        p += __shfl_xor(p, 2, 64);
        p += __shfl_xor(p, 4, 64);
        p += __shfl_xor(p, 8, 64);
        mx = fmaxf(mx, p);
        sm += p;
    }
    if ((lane & 15) == 0) measure[(size_t)bh * LL + i] = mx - sm * (1.0f / LL);
}

// ---------------- K3: exact top-40 per (b,h), lax.top_k tie semantics -------
__global__ __launch_bounds__(256) void topk_kernel(const float* __restrict__ measure,
                                                   int* __restrict__ q_idx,
                                                   int* __restrict__ sel_pos) {
    __shared__ float ms[LL];
    __shared__ float wvv[4];
    __shared__ int wvi[4];
    const int t = threadIdx.x;
    const int bh = blockIdx.x;
    for (int i = t; i < LL; i += 256) {
        ms[i] = measure[(size_t)bh * LL + i];
        sel_pos[(size_t)bh * LL + i] = -1;
    }
    __syncthreads();
    for (int it = 0; it < NUMQ; ++it) {
        float bv = -INFINITY; int bi = 0x7fffffff;
        for (int i = t; i < LL; i += 256) {
            float v = ms[i];
            if (v > bv) { bv = v; bi = i; }
        }
#pragma unroll
        for (int off = 32; off > 0; off >>= 1) {
            float ov = __shfl_xor(bv, off, 64);
            int   oi = __shfl_xor(bi, off, 64);
            if (ov > bv || (ov == bv && oi < bi)) { bv = ov; bi = oi; }
        }
        if ((t & 63) == 0) { wvv[t >> 6] = bv; wvi[t >> 6] = bi; }
        __syncthreads();
        if (t == 0) {
            float fv = wvv[0]; int fi = wvi[0];
#pragma unroll
            for (int u = 1; u < 4; ++u)
                if (wvv[u] > fv || (wvv[u] == fv && wvi[u] < fi)) { fv = wvv[u]; fi = wvi[u]; }
            q_idx[bh * NUMQ + it] = fi;
            sel_pos[(size_t)bh * LL + fi] = it;
            ms[fi] = -INFINITY;
        }
        __syncthreads();
    }
}

// ---------------- K4: attn v2 — block = (bh, 4 queries) ---------------------
// grid (16, 10). K/V read once per block; scores in regs + LDS.
__global__ __launch_bounds__(256) void attn_kernel(const float* __restrict__ qp2,
                                                   const float* __restrict__ kpt,
                                                   const float* __restrict__ vp2,
                                                   const int* __restrict__ q_idx,
                                                   float* __restrict__ attn_out,
                                                   float* __restrict__ out_sel) {
    __shared__ float qs[4][DD];
    __shared__ float sc[4][LL];       // 32 KB, unnormalized exp values
    __shared__ float wred[4][4];      // [wave][q]
    __shared__ float pvred[16][68];
    const int t = threadIdx.x;
    const int lane = t & 63, w = t >> 6;
    const int bh = blockIdx.x;
    const int qg = blockIdx.y;
    // stage 4 q rows
    {
        const int qq = t >> 6, d = t & 63;
        const int qi = q_idx[bh * NUMQ + qg * 4 + qq];
        qs[qq][d] = qp2[((size_t)bh * LL + qi) * DD + d];
    }
    __syncthreads();

    // ---- QK^T: thread t owns keys [4t,4t+4) and [1024+4t, ...) ----
    const float* kbase = kpt + (size_t)bh * DD * LL;
    float4 acc[4][2];
#pragma unroll
    for (int qq = 0; qq < 4; ++qq) {
        acc[qq][0] = make_float4(0.f, 0.f, 0.f, 0.f);
        acc[qq][1] = make_float4(0.f, 0.f, 0.f, 0.f);
    }
    for (int d = 0; d < DD; ++d) {
        const float4 k0 = *(const float4*)(kbase + (size_t)d * LL + 4 * t);
        const float4 k1 = *(const float4*)(kbase + (size_t)d * LL + 1024 + 4 * t);
#pragma unroll
        for (int qq = 0; qq < 4; ++qq) {
            const float qv = qs[qq][d];
            acc[qq][0].x = fmaf(qv, k0.x, acc[qq][0].x);
            acc[qq][0].y = fmaf(qv, k0.y, acc[qq][0].y);
            acc[qq][0].z = fmaf(qv, k0.z, acc[qq][0].z);
            acc[qq][0].w = fmaf(qv, k0.w, acc[qq][0].w);
            acc[qq][1].x = fmaf(qv, k1.x, acc[qq][1].x);
            acc[qq][1].y = fmaf(qv, k1.y, acc[qq][1].y);
            acc[qq][1].z = fmaf(qv, k1.z, acc[qq][1].z);
            acc[qq][1].w = fmaf(qv, k1.w, acc[qq][1].w);
        }
    }
    // ---- scale + per-q max ----
    const float scale = 0.125f;
    float mx[4];
#pragma unroll
    for (int qq = 0; qq < 4; ++qq) {
        acc[qq][0].x *= scale; acc[qq][0].y *= scale; acc[qq][0].z *= scale; acc[qq][0].w *= scale;
        acc[qq][1].x *= scale; acc[qq][1].y *= scale; acc[qq][1].z *= scale; acc[qq][1].w *= scale;
        float m = fmaxf(fmaxf(fmaxf(acc[qq][0].x, acc[qq][0].y), fmaxf(acc[qq][0].z, acc[qq][0].w)),
                        fmaxf(fmaxf(acc[qq][1].x, acc[qq][1].y), fmaxf(acc[qq][1].z, acc[qq][1].w)));
#pragma unroll
        for (int off = 32; off > 0; off >>= 1) m = fmaxf(m, __shfl_xor(m, off, 64));
        mx[qq] = m;
        if (lane == 0) wred[w][qq] = m;
    }
    __syncthreads();
#pragma unroll
    for (int qq = 0; qq < 4; ++qq)
        mx[qq] = fmaxf(fmaxf(wred[0][qq], wred[1][qq]), fmaxf(wred[2][qq], wred[3][qq]));
    __syncthreads();   // protect wred before sum phase overwrites

    // ---- exp (keep in regs), store unnormalized to sc, per-q sum ----
    float sm[4];
#pragma unroll
    for (int qq = 0; qq < 4; ++qq) {
        acc[qq][0].x = __expf(acc[qq][0].x - mx[qq]);
        acc[qq][0].y = __expf(acc[qq][0].y - mx[qq]);
        acc[qq][0].z = __expf(acc[qq][0].z - mx[qq]);
        acc[qq][0].w = __expf(acc[qq][0].w - mx[qq]);
        acc[qq][1].x = __expf(acc[qq][1].x - mx[qq]);
        acc[qq][1].y = __expf(acc[qq][1].y - mx[qq]);
        acc[qq][1].z = __expf(acc[qq][1].z - mx[qq]);
        acc[qq][1].w = __expf(acc[qq][1].w - mx[qq]);
        *(float4*)&sc[qq][4 * t] = acc[qq][0];
        *(float4*)&sc[qq][1024 + 4 * t] = acc[qq][1];
        float s = (acc[qq][0].x + acc[qq][0].y + acc[qq][0].z + acc[qq][0].w)
                + (acc[qq][1].x + acc[qq][1].y + acc[qq][1].z + acc[qq][1].w);
#pragma unroll
        for (int off = 32; off > 0; off >>= 1) s += __shfl_xor(s, off, 64);
        sm[qq] = s;
        if (lane == 0) wred[w][qq] = s;
    }
    __syncthreads();
    float inv[4];
#pragma unroll
    for (int qq = 0; qq < 4; ++qq)
        inv[qq] = 1.0f / (wred[0][qq] + wred[1][qq] + wred[2][qq] + wred[3][qq]);

    // ---- write normalized attn rows (coalesced) ----
#pragma unroll
    for (int qq = 0; qq < 4; ++qq) {
        float* arow = attn_out + ((size_t)(bh * NUMQ + qg * 4 + qq)) * LL;
        float4 w0 = make_float4(acc[qq][0].x * inv[qq], acc[qq][0].y * inv[qq],
                                acc[qq][0].z * inv[qq], acc[qq][0].w * inv[qq]);
        float4 w1 = make_float4(acc[qq][1].x * inv[qq], acc[qq][1].y * inv[qq],
                                acc[qq][1].z * inv[qq], acc[qq][1].w * inv[qq]);
        *(float4*)&arow[4 * t] = w0;
        *(float4*)&arow[1024 + 4 * t] = w1;
    }

    // ---- PV: V read once, 4 query accumulators ----
    const int lg = t >> 4, dq = (t & 15) * 4;
    float4 pv[4];
#pragma unroll
    for (int qq = 0; qq < 4; ++qq) pv[qq] = make_float4(0.f, 0.f, 0.f, 0.f);
    const float* vbase = vp2 + (size_t)bh * LL * DD + dq;
    for (int l = lg; l < LL; l += 16) {
        const float4 vv = *(const float4*)(vbase + (size_t)l * DD);
#pragma unroll
        for (int qq = 0; qq < 4; ++qq) {
            const float pr = sc[qq][l];
            pv[qq].x = fmaf(pr, vv.x, pv[qq].x);
            pv[qq].y = fmaf(pr, vv.y, pv[qq].y);
            pv[qq].z = fmaf(pr, vv.z, pv[qq].z);
            pv[qq].w = fmaf(pr, vv.w, pv[qq].w);
        }
    }
#pragma unroll
    for (int qq = 0; qq < 4; ++qq) {
        __syncthreads();
        *(float4*)&pvred[lg][dq] = pv[qq];
        __syncthreads();
        if (t < DD) {
            float s = 0.f;
#pragma unroll
            for (int u = 0; u < 16; ++u) s += pvred[u][t];
            out_sel[((size_t)bh * NUMQ + qg * 4 + qq) * DD + t] = s * inv[qq];
        }
    }
}

// ---------------- K5: v_mean, two-stage ------------------------------------
__global__ __launch_bounds__(256) void vmean1_kernel(const float* __restrict__ vp2,
                                                     float* __restrict__ partial) {
    __shared__ float pv[256];
    const int t = threadIdx.x;
    const int chunk = blockIdx.x & 31;
    const int bh = blockIdx.x >> 5;
    const int d = t & 63, g = t >> 6;
    const int l0 = chunk * 64;
    float acc = 0.f;
    for (int l = l0 + g; l < l0 + 64; l += 4)
        acc += vp2[((size_t)bh * LL + l) * DD + d];
    pv[t] = acc;
    __syncthreads();
    if (t < 64)
        partial[(size_t)blockIdx.x * 64 + t] = pv[t] + pv[64 + t] + pv[128 + t] + pv[192 + t];
}

__global__ __launch_bounds__(64) void vmean2_kernel(const float* __restrict__ partial,
                                                    float* __restrict__ v_mean) {
    const int bh = blockIdx.x;
    const int t = threadIdx.x;
    float s = 0.f;
    for (int c = 0; c < 32; ++c)
        s += partial[((size_t)bh * 32 + c) * 64 + t];
    v_mean[bh * 64 + t] = s * (1.0f / LL);
}

// ---------------- K6: scatter + residual + LayerNorm ------------------------
__global__ __launch_bounds__(512) void final_kernel(const float* __restrict__ q_in,
                                                    const int* __restrict__ sel_pos,
                                                    const float* __restrict__ out_sel,
                                                    const float* __restrict__ v_mean,
                                                    const float* __restrict__ gamma,
                                                    const float* __restrict__ beta,
                                                    float* __restrict__ yout) {
    __shared__ float wred[8];
    const int j = threadIdx.x;
    const int lane = j & 63, wv = j >> 6;
    const int tok = blockIdx.x;          // b*L + l
    const int b = tok >> 11;
    const int l = tok & (LL - 1);
    const int h = wv, d = lane;
    const int bh = b * HH + h;
    const int p = sel_pos[(size_t)bh * LL + l];
    float val = (p >= 0) ? out_sel[((size_t)bh * NUMQ + p) * DD + d]
                         : v_mean[bh * DD + d];
    float y = val + q_in[(size_t)tok * DMM + j];
    float s = y;
#pragma unroll
    for (int off = 32; off > 0; off >>= 1) s += __shfl_xor(s, off, 64);
    if (lane == 0) wred[wv] = s;
    __syncthreads();
    float tot = 0.f;
#pragma unroll
    for (int u = 0; u < 8; ++u) tot += wred[u];
    float mu = tot * (1.0f / DMM);
    __syncthreads();
    float dv = y - mu;
    float s2 = dv * dv;
#pragma unroll
    for (int off = 32; off > 0; off >>= 1) s2 += __shfl_xor(s2, off, 64);
    if (lane == 0) wred[wv] = s2;
    __syncthreads();
    float tot2 = 0.f;
#pragma unroll
    for (int u = 0; u < 8; ++u) tot2 += wred[u];
    float var = tot2 * (1.0f / DMM);
    float yn = dv * rsqrtf(var + LNEPS) * gamma[j] + beta[j];
    yout[(size_t)tok * DMM + j] = yn;
}

extern "C" void kernel_launch(void* const* d_in, const int* in_sizes, int n_in,
                              void* d_out, int out_size, void* d_ws, size_t ws_size,
                              hipStream_t stream) {
    const float* q     = (const float*)d_in[0];
    const float* k     = (const float*)d_in[1];
    const float* v     = (const float*)d_in[2];
    const float* Wq    = (const float*)d_in[3];
    const float* bq    = (const float*)d_in[4];
    const float* Wk    = (const float*)d_in[5];
    const float* bk    = (const float*)d_in[6];
    const float* Wv    = (const float*)d_in[7];
    const float* bv    = (const float*)d_in[8];
    const float* gamma = (const float*)d_in[9];
    const float* beta  = (const float*)d_in[10];
    const int*   rnd   = (const int*)d_in[11];

    float* ws = (float*)d_ws;
    const size_t proj_sz = (size_t)BB * HH * LL * DD;      // = B*L*DM elements
    float* qp2     = ws;
    float* kp2     = qp2 + proj_sz;
    float* vp2     = kp2 + proj_sz;
    float* kpt     = vp2 + proj_sz;
    float* measure = kpt + proj_sz;                        // B*H*L
    float* out_sel = measure + (size_t)BB * HH * LL;       // B*H*NUMQ*D
    float* v_mean  = out_sel + (size_t)BB * HH * NUMQ * DD;// B*H*D
    float* partial = v_mean + (size_t)BB * HH * DD;        // B*H*32*64
    int*   q_idx   = (int*)(partial + (size_t)BB * HH * 32 * 64);
    int*   sel_pos = q_idx + BB * HH * NUMQ;               // B*H*L
    ushort_t* Xh  = (ushort_t*)(sel_pos + BB * HH * LL);
    ushort_t* Xl  = Xh + 3 * proj_sz;
    ushort_t* Wht = Xl + 3 * proj_sz;
    ushort_t* Wlt = Wht + 3 * (size_t)DMM * DMM;

    float* yn_out   = (float*)d_out;
    float* attn_out = yn_out + (size_t)BB * LL * DMM;

    convert_x_kernel<<<dim3(BB * LL * DMM / (256 * 8), 3), 256, 0, stream>>>(q, k, v, Xh, Xl);
    convert_w_kernel<<<dim3(DMM / 64, DMM / 64, 3), 256, 0, stream>>>(Wq, Wk, Wv, Wht, Wlt);
    proj_mfma_kernel<<<dim3(BB * LL / 64, DMM / 64, 3), 256, 0, stream>>>(
        Xh, Xl, Wht, Wlt, bq, bk, bv, qp2, kp2, vp2);
    transpose_kernel<<<dim3(LL / 64, BB * HH), 256, 0, stream>>>(kp2, kpt);
    vmean1_kernel<<<BB * HH * 32, 256, 0, stream>>>(vp2, partial);
    vmean2_kernel<<<BB * HH, 64, 0, stream>>>(partial, v_mean);
    measure_kernel<<<dim3(BB * HH, LL / 16), 256, 0, stream>>>(qp2, kp2, rnd, measure);
    topk_kernel<<<BB * HH, 256, 0, stream>>>(measure, q_idx, sel_pos);
    attn_kernel<<<dim3(BB * HH, NUMQ / 4), 256, 0, stream>>>(qp2, kpt, vp2, q_idx, attn_out, out_sel);
    final_kernel<<<BB * LL, 512, 0, stream>>>(q, sel_pos, out_sel, v_mean, gamma, beta, yn_out);
}